// Round 1
// baseline (98.958 us; speedup 1.0000x reference)
//
#include <hip/hip_runtime.h>
#include <hip/hip_bf16.h>

// Fully fused MLP: 32 -> 64 -> (4x) 64 -> 3, relu hidden, sigmoid out.
// bf16 MFMA (16x16x32), fp32 accum. N = 1<<20 points, fp32 I/O.
//
// Layout notes:
//  - A-frag (activations): lane holds A[l&15][8*(l>>4)+b], b=0..7 (contiguous k) -> ds_read_b128.
//  - B-frag (weights):     lane holds B[k][l&15] = W[l&15][k], same k pattern -> row-major [o][k] in LDS.
//  - D-frag: col = lane&15, row = 4*(lane>>4)+r  (HW-verified layout).
//  - sigma(n) = 4*(n&15) + (n>>4) permutes the hidden-neuron order. Applied at weight/bias
//    STAGING time to the k-dim of the next layer's weights, it makes each lane's 4 same-row
//    D values LDS-contiguous -> one ds_write_b64 per acc row (instead of 16x ds_write_b16).

typedef __attribute__((ext_vector_type(8))) short bf16x8;
typedef __attribute__((ext_vector_type(4))) float f32x4;

#define WIN_STRIDE 40   // W_in row stride (bf16), K=32; 80B rows keep b128 16B-aligned
#define W_STRIDE   72   // hidden/out weight row stride (bf16), K=64; 144B rows, 16B-aligned
#define H_STRIDE   72   // activation row stride

__device__ __forceinline__ unsigned short f2bf(float f) {
    __hip_bfloat16 h = __float2bfloat16(f);   // RNE
    unsigned short u;
    __builtin_memcpy(&u, &h, 2);
    return u;
}

__device__ __forceinline__ unsigned int pk2(float a, float b) {
    return (unsigned int)f2bf(a) | ((unsigned int)f2bf(b) << 16);
}

struct __align__(16) MlpLds {
    unsigned short w_in[64 * WIN_STRIDE];     // [o][k] natural            5120 B
    unsigned short w_hid[4 * 64 * W_STRIDE];  // [L][o][sigma(k)]         36864 B
    unsigned short w_out[3 * W_STRIDE];       // [o][sigma(k)]              432 B
    float          b_in[64];                  // [sigma(n)]                 256 B
    float          b_hid[4 * 64];             // [L][sigma(n)]             1024 B
    float          b_out[4];                  //                             16 B
    unsigned short H[8][2][16 * H_STRIDE];    // [wave][tile][row][sig-col] 36864 B
};                                            // total 80576 B -> 2 blocks/CU

__global__ __launch_bounds__(512, 4) void mlp_kernel(
        const float* __restrict__ x,
        const float* __restrict__ gW_in,  const float* __restrict__ gb_in,
        const float* __restrict__ gW_hid, const float* __restrict__ gb_hid,
        const float* __restrict__ gW_out, const float* __restrict__ gb_out,
        float* __restrict__ out) {
    __shared__ MlpLds s;
    const int tid = threadIdx.x;

    // ---------------- stage weights/biases (f32 -> bf16, sigma on k of hidden/out) --------
    for (int e = tid; e < 64 * 32; e += 512) {
        int o = e >> 5, k = e & 31;
        s.w_in[o * WIN_STRIDE + k] = f2bf(gW_in[e]);
    }
    for (int e = tid; e < 4 * 64 * 64; e += 512) {
        int L = e >> 12, o = (e >> 6) & 63, k = e & 63;
        int sk = 4 * (k & 15) + (k >> 4);
        s.w_hid[(L * 64 + o) * W_STRIDE + sk] = f2bf(gW_hid[e]);
    }
    for (int e = tid; e < 3 * 64; e += 512) {
        int o = e >> 6, k = e & 63;
        int sk = 4 * (k & 15) + (k >> 4);
        s.w_out[o * W_STRIDE + sk] = f2bf(gW_out[e]);
    }
    for (int e = tid; e < 64; e += 512)
        s.b_in[4 * (e & 15) + (e >> 4)] = gb_in[e];
    for (int e = tid; e < 4 * 64; e += 512) {
        int L = e >> 6, n = e & 63;
        s.b_hid[L * 64 + 4 * (n & 15) + (n >> 4)] = gb_hid[e];
    }
    if (tid < 4) s.b_out[tid] = (tid < 3) ? gb_out[tid] : 0.f;
    __syncthreads();

    // ---------------- per-wave compute: 2 tiles of 16 rows ----------------
    const int wave = tid >> 6;
    const int lane = tid & 63;
    const int j = lane & 15;   // frag col / A row
    const int g = lane >> 4;   // k-group
    const int wgid = blockIdx.x * 8 + wave;        // 0..32767
    int rb[2] = { wgid * 32, wgid * 32 + 16 };
    unsigned short* Hb[2] = { s.H[wave][0], s.H[wave][1] };

    // ======== input layer: h0 = relu(x @ W_in^T + b_in) ========
    bf16x8 win[4];
#pragma unroll
    for (int nt = 0; nt < 4; ++nt)
        win[nt] = *(const bf16x8*)&s.w_in[(nt * 16 + j) * WIN_STRIDE + 8 * g];
    f32x4 bvin = *(const f32x4*)&s.b_in[4 * j];
#pragma unroll
    for (int t = 0; t < 2; ++t) {
        const float* xr = x + (size_t)(rb[t] + j) * 32 + 8 * g;
        f32x4 f0 = *(const f32x4*)xr;
        f32x4 f1 = *(const f32x4*)(xr + 4);
        bf16x8 a;
        a[0] = (short)f2bf(f0[0]); a[1] = (short)f2bf(f0[1]);
        a[2] = (short)f2bf(f0[2]); a[3] = (short)f2bf(f0[3]);
        a[4] = (short)f2bf(f1[0]); a[5] = (short)f2bf(f1[1]);
        a[6] = (short)f2bf(f1[2]); a[7] = (short)f2bf(f1[3]);
        f32x4 acc[4];
#pragma unroll
        for (int nt = 0; nt < 4; ++nt) {
            f32x4 z = {0.f, 0.f, 0.f, 0.f};
            acc[nt] = __builtin_amdgcn_mfma_f32_16x16x32_bf16(a, win[nt], z, 0, 0, 0);
        }
#pragma unroll
        for (int r = 0; r < 4; ++r) {
            float v0 = fmaxf(acc[0][r] + bvin[0], 0.f);
            float v1 = fmaxf(acc[1][r] + bvin[1], 0.f);
            float v2 = fmaxf(acc[2][r] + bvin[2], 0.f);
            float v3 = fmaxf(acc[3][r] + bvin[3], 0.f);
            uint2 pw = { pk2(v0, v1), pk2(v2, v3) };
            *(uint2*)&Hb[t][(4 * g + r) * H_STRIDE + 4 * j] = pw;
        }
    }

    // ======== 4 hidden layers: h = relu(h @ W^T + b), sigma-space k ========
#pragma unroll
    for (int L = 0; L < 4; ++L) {
        bf16x8 wf[4][2];
#pragma unroll
        for (int nt = 0; nt < 4; ++nt) {
            const unsigned short* wl = &s.w_hid[(L * 64 + nt * 16 + j) * W_STRIDE + 8 * g];
            wf[nt][0] = *(const bf16x8*)(wl);
            wf[nt][1] = *(const bf16x8*)(wl + 32);
        }
        f32x4 bv = *(const f32x4*)&s.b_hid[L * 64 + 4 * j];
#pragma unroll
        for (int t = 0; t < 2; ++t) {
            bf16x8 a0 = *(const bf16x8*)&Hb[t][j * H_STRIDE + 8 * g];
            bf16x8 a1 = *(const bf16x8*)&Hb[t][j * H_STRIDE + 32 + 8 * g];
            f32x4 acc[4];
#pragma unroll
            for (int nt = 0; nt < 4; ++nt) {
                f32x4 z = {0.f, 0.f, 0.f, 0.f};
                z = __builtin_amdgcn_mfma_f32_16x16x32_bf16(a0, wf[nt][0], z, 0, 0, 0);
                acc[nt] = __builtin_amdgcn_mfma_f32_16x16x32_bf16(a1, wf[nt][1], z, 0, 0, 0);
            }
#pragma unroll
            for (int r = 0; r < 4; ++r) {
                float v0 = fmaxf(acc[0][r] + bv[0], 0.f);
                float v1 = fmaxf(acc[1][r] + bv[1], 0.f);
                float v2 = fmaxf(acc[2][r] + bv[2], 0.f);
                float v3 = fmaxf(acc[3][r] + bv[3], 0.f);
                uint2 pw = { pk2(v0, v1), pk2(v2, v3) };
                *(uint2*)&Hb[t][(4 * g + r) * H_STRIDE + 4 * j] = pw;
            }
        }
    }

    // ======== output layer: sigmoid(h @ W_out^T + b_out), 3 valid cols ========
    bf16x8 wo0 = {0,0,0,0,0,0,0,0};
    bf16x8 wo1 = {0,0,0,0,0,0,0,0};
    if (j < 3) {
        wo0 = *(const bf16x8*)&s.w_out[j * W_STRIDE + 8 * g];
        wo1 = *(const bf16x8*)&s.w_out[j * W_STRIDE + 32 + 8 * g];
    }
    float bo = s.b_out[j & 3];
#pragma unroll
    for (int t = 0; t < 2; ++t) {
        bf16x8 a0 = *(const bf16x8*)&Hb[t][j * H_STRIDE + 8 * g];
        bf16x8 a1 = *(const bf16x8*)&Hb[t][j * H_STRIDE + 32 + 8 * g];
        f32x4 z = {0.f, 0.f, 0.f, 0.f};
        z = __builtin_amdgcn_mfma_f32_16x16x32_bf16(a0, wo0, z, 0, 0, 0);
        f32x4 acc = __builtin_amdgcn_mfma_f32_16x16x32_bf16(a1, wo1, z, 0, 0, 0);
        if (j < 3) {
#pragma unroll
            for (int r = 0; r < 4; ++r) {
                float v = acc[r] + bo;
                v = 1.f / (1.f + __expf(-v));
                out[(size_t)(rb[t] + 4 * g + r) * 3 + j] = v;
            }
        }
    }
}

extern "C" void kernel_launch(void* const* d_in, const int* in_sizes, int n_in,
                              void* d_out, int out_size, void* d_ws, size_t ws_size,
                              hipStream_t stream) {
    const float* x     = (const float*)d_in[0];
    const float* W_in  = (const float*)d_in[1];
    const float* b_in  = (const float*)d_in[2];
    const float* W_hid = (const float*)d_in[3];
    const float* b_hid = (const float*)d_in[4];
    const float* W_out = (const float*)d_in[5];
    const float* b_out = (const float*)d_in[6];
    float* out = (float*)d_out;

    int n = in_sizes[0] / 32;            // 1<<20
    int nblocks = n / 256;               // 8 waves * 2 tiles * 16 rows per block
    hipLaunchKernelGGL(mlp_kernel, dim3(nblocks), dim3(512), 0, stream,
                       x, W_in, b_in, W_hid, b_hid, W_out, b_out, out);
}

// Round 2
// 68.804 us; speedup vs baseline: 1.4382x; 1.4382x over previous
//
#include <hip/hip_runtime.h>
#include <hip/hip_bf16.h>

// Fully fused MLP: 32 -> 64 -> (4x) 64 -> 3, relu hidden, sigmoid out.
// bf16 MFMA (16x16x32), fp32 accum. N = 1<<20 points, fp32 I/O.
//
// Round-2 changes vs round-1 (VALU-bound, 63% VALUBusy / 14% MfmaUtil):
//  1. prep_kernel pre-builds the 44KB LDS weight image (bf16 + sigma permutation +
//     permuted biases) in d_ws once per launch; main blocks do a LINEAR uint4 copy
//     (~50 VALU/thread instead of ~500 of index math + NaN-checked cvt).
//  2. all f32->bf16 packing uses v_cvt_pk_bf16_f32 (1 instr / 2 values).
//  3. bias folded into the MFMA C operand (broadcast once per layer, hoisted).
//
// Layout (unchanged, HW-verified D layout col=lane&15,row=4*(lane>>4)+r):
//  sigma(n) = 4*(n&15) + (n>>4) applied at staging to next-layer k indices makes
//  each lane's 4 same-row D values LDS-contiguous -> single b64 write per acc row.

typedef __attribute__((ext_vector_type(8))) short bf16x8;
typedef __attribute__((ext_vector_type(4))) float f32x4;

#define WIN_STRIDE 40   // W_in row stride (bf16), K=32; 80B rows, b128-aligned
#define W_STRIDE   72   // hidden/out weight row stride (bf16), K=64; 144B rows
#define H_STRIDE   72   // activation row stride

// stage image byte offsets (16B-aligned where b128/f32x4 reads happen)
#define W_IN_OFF    0        // 64*40*2   = 5120
#define W_HID_OFF   5120     // 4*64*72*2 = 36864
#define W_OUT_OFF   41984    // 3*72*2    = 432
#define B_IN_OFF    42416    // 64*4      = 256
#define B_HID_OFF   42672    // 4*64*4    = 1024
#define B_OUT_OFF   43696    // 4*4       = 16
#define STAGE_BYTES 44032    // padded to 43 * 1024

__device__ __forceinline__ unsigned short f2bf(float f) {
    __hip_bfloat16 h = __float2bfloat16(f);   // RNE (prep kernel only)
    unsigned short u;
    __builtin_memcpy(&u, &h, 2);
    return u;
}

// packed f32x2 -> bf16x2, RNE, 1 instruction. lo = src0, hi = src1.
__device__ __forceinline__ unsigned cvtpk(float lo, float hi) {
    unsigned r;
    asm("v_cvt_pk_bf16_f32 %0, %1, %2" : "=v"(r) : "v"(lo), "v"(hi));
    return r;
}

__device__ __forceinline__ int sigma(int n) { return 4 * (n & 15) + (n >> 4); }

// ---------------- prep: build the LDS weight image in d_ws ----------------
__global__ void prep_kernel(const float* __restrict__ W_in,  const float* __restrict__ b_in,
                            const float* __restrict__ W_hid, const float* __restrict__ b_hid,
                            const float* __restrict__ W_out, const float* __restrict__ b_out,
                            unsigned char* __restrict__ img) {
    const int tid = blockIdx.x * blockDim.x + threadIdx.x;
    const int stride = gridDim.x * blockDim.x;
    unsigned short* w_in  = (unsigned short*)(img + W_IN_OFF);
    unsigned short* w_hid = (unsigned short*)(img + W_HID_OFF);
    unsigned short* w_out = (unsigned short*)(img + W_OUT_OFF);
    float* bin  = (float*)(img + B_IN_OFF);
    float* bhid = (float*)(img + B_HID_OFF);
    float* bout = (float*)(img + B_OUT_OFF);

    for (int e = tid; e < 64 * 32; e += stride) {
        int o = e >> 5, k = e & 31;
        w_in[o * WIN_STRIDE + k] = f2bf(W_in[e]);
    }
    for (int e = tid; e < 4 * 64 * 64; e += stride) {
        int L = e >> 12, o = (e >> 6) & 63, k = e & 63;
        w_hid[(L * 64 + o) * W_STRIDE + sigma(k)] = f2bf(W_hid[e]);
    }
    for (int e = tid; e < 3 * 64; e += stride) {
        int o = e >> 6, k = e & 63;
        w_out[o * W_STRIDE + sigma(k)] = f2bf(W_out[e]);
    }
    for (int e = tid; e < 64; e += stride)  bin[sigma(e)] = b_in[e];
    for (int e = tid; e < 4 * 64; e += stride) {
        int L = e >> 6, n = e & 63;
        bhid[L * 64 + sigma(n)] = b_hid[e];
    }
    if (tid < 4) bout[tid] = (tid < 3) ? b_out[tid] : 0.f;
}

// ---------------- main fused kernel ----------------
struct __align__(16) MlpLds {
    unsigned char  stage[STAGE_BYTES];        // 44032 B weight/bias image
    unsigned short H[8][2][16 * H_STRIDE];    // [wave][tile][row][sig-col] 36864 B
};                                            // total 80896 B -> 2 blocks/CU

template<bool FAST>
__global__ __launch_bounds__(512, 4) void mlp_kernel(
        const float* __restrict__ x,
        const float* __restrict__ gW_in,  const float* __restrict__ gb_in,
        const float* __restrict__ gW_hid, const float* __restrict__ gb_hid,
        const float* __restrict__ gW_out, const float* __restrict__ gb_out,
        const uint4* __restrict__ img,
        float* __restrict__ out) {
    __shared__ MlpLds s;
    const int tid = threadIdx.x;
    const int wave = tid >> 6;
    const int lane = tid & 63;

    if (FAST) {
        // linear copy of the prebuilt image: 43 chunks of 1KB, one per wave-iter
        uint4* dst = (uint4*)s.stage;
        for (int c = wave; c < STAGE_BYTES / 1024; c += 8) {
            int idx = c * 64 + lane;
            dst[idx] = img[idx];
        }
    } else {
        // fallback self-staging (ws too small): same math as prep_kernel
        unsigned short* w_in  = (unsigned short*)(s.stage + W_IN_OFF);
        unsigned short* w_hid = (unsigned short*)(s.stage + W_HID_OFF);
        unsigned short* w_out = (unsigned short*)(s.stage + W_OUT_OFF);
        float* bin  = (float*)(s.stage + B_IN_OFF);
        float* bhid = (float*)(s.stage + B_HID_OFF);
        float* bout = (float*)(s.stage + B_OUT_OFF);
        for (int e = tid; e < 64 * 32; e += 512) {
            int o = e >> 5, k = e & 31;
            w_in[o * WIN_STRIDE + k] = f2bf(gW_in[e]);
        }
        for (int e = tid; e < 4 * 64 * 64; e += 512) {
            int L = e >> 12, o = (e >> 6) & 63, k = e & 63;
            w_hid[(L * 64 + o) * W_STRIDE + sigma(k)] = f2bf(gW_hid[e]);
        }
        for (int e = tid; e < 3 * 64; e += 512) {
            int o = e >> 6, k = e & 63;
            w_out[o * W_STRIDE + sigma(k)] = f2bf(gW_out[e]);
        }
        for (int e = tid; e < 64; e += 512) bin[sigma(e)] = gb_in[e];
        for (int e = tid; e < 4 * 64; e += 512) {
            int L = e >> 6, n = e & 63;
            bhid[L * 64 + sigma(n)] = gb_hid[e];
        }
        if (tid < 4) bout[tid] = (tid < 3) ? gb_out[tid] : 0.f;
    }
    __syncthreads();

    const unsigned short* w_in  = (const unsigned short*)(s.stage + W_IN_OFF);
    const unsigned short* w_hid = (const unsigned short*)(s.stage + W_HID_OFF);
    const unsigned short* w_out = (const unsigned short*)(s.stage + W_OUT_OFF);
    const float* bin  = (const float*)(s.stage + B_IN_OFF);
    const float* bhid = (const float*)(s.stage + B_HID_OFF);
    const float* bout = (const float*)(s.stage + B_OUT_OFF);

    const int j = lane & 15;   // frag col / A row
    const int g = lane >> 4;   // k-group
    const int wgid = blockIdx.x * 8 + wave;
    const int rb0 = wgid * 32;
    unsigned short* Hb[2] = { &s.H[wave][0][0], &s.H[wave][1][0] };

    // ======== input layer: h0 = relu(x @ W_in^T + b_in) ========
    bf16x8 win[4];
#pragma unroll
    for (int nt = 0; nt < 4; ++nt)
        win[nt] = *(const bf16x8*)&w_in[(nt * 16 + j) * WIN_STRIDE + 8 * g];
    f32x4 bvin = *(const f32x4*)&bin[4 * j];
    f32x4 zin[4];
#pragma unroll
    for (int nt = 0; nt < 4; ++nt)
        zin[nt] = f32x4{bvin[nt], bvin[nt], bvin[nt], bvin[nt]};
#pragma unroll
    for (int t = 0; t < 2; ++t) {
        const float* xr = x + (size_t)(rb0 + t * 16 + j) * 32 + 8 * g;
        f32x4 f0 = *(const f32x4*)xr;
        f32x4 f1 = *(const f32x4*)(xr + 4);
        union { bf16x8 v; unsigned u[4]; } au;
        au.u[0] = cvtpk(f0[0], f0[1]);
        au.u[1] = cvtpk(f0[2], f0[3]);
        au.u[2] = cvtpk(f1[0], f1[1]);
        au.u[3] = cvtpk(f1[2], f1[3]);
        f32x4 acc[4];
#pragma unroll
        for (int nt = 0; nt < 4; ++nt)
            acc[nt] = __builtin_amdgcn_mfma_f32_16x16x32_bf16(au.v, win[nt], zin[nt], 0, 0, 0);
#pragma unroll
        for (int r = 0; r < 4; ++r) {
            float v0 = fmaxf(acc[0][r], 0.f);
            float v1 = fmaxf(acc[1][r], 0.f);
            float v2 = fmaxf(acc[2][r], 0.f);
            float v3 = fmaxf(acc[3][r], 0.f);
            uint2 pw = { cvtpk(v0, v1), cvtpk(v2, v3) };
            *(uint2*)&Hb[t][(4 * g + r) * H_STRIDE + 4 * j] = pw;
        }
    }

    // ======== 4 hidden layers: h = relu(h @ W^T + b), sigma-space k ========
#pragma unroll
    for (int L = 0; L < 4; ++L) {
        bf16x8 wf[4][2];
#pragma unroll
        for (int nt = 0; nt < 4; ++nt) {
            const unsigned short* wl = &w_hid[(L * 64 + nt * 16 + j) * W_STRIDE + 8 * g];
            wf[nt][0] = *(const bf16x8*)(wl);
            wf[nt][1] = *(const bf16x8*)(wl + 32);
        }
        f32x4 bv = *(const f32x4*)&bhid[L * 64 + 4 * j];
        f32x4 zb[4];
#pragma unroll
        for (int nt = 0; nt < 4; ++nt)
            zb[nt] = f32x4{bv[nt], bv[nt], bv[nt], bv[nt]};
#pragma unroll
        for (int t = 0; t < 2; ++t) {
            bf16x8 a0 = *(const bf16x8*)&Hb[t][j * H_STRIDE + 8 * g];
            bf16x8 a1 = *(const bf16x8*)&Hb[t][j * H_STRIDE + 32 + 8 * g];
            f32x4 acc[4];
#pragma unroll
            for (int nt = 0; nt < 4; ++nt) {
                f32x4 z = __builtin_amdgcn_mfma_f32_16x16x32_bf16(a0, wf[nt][0], zb[nt], 0, 0, 0);
                acc[nt] = __builtin_amdgcn_mfma_f32_16x16x32_bf16(a1, wf[nt][1], z, 0, 0, 0);
            }
#pragma unroll
            for (int r = 0; r < 4; ++r) {
                float v0 = fmaxf(acc[0][r], 0.f);
                float v1 = fmaxf(acc[1][r], 0.f);
                float v2 = fmaxf(acc[2][r], 0.f);
                float v3 = fmaxf(acc[3][r], 0.f);
                uint2 pw = { cvtpk(v0, v1), cvtpk(v2, v3) };
                *(uint2*)&Hb[t][(4 * g + r) * H_STRIDE + 4 * j] = pw;
            }
        }
    }

    // ======== output layer: sigmoid(h @ W_out^T + b_out), 3 valid cols ========
    bf16x8 wo0 = {0,0,0,0,0,0,0,0};
    bf16x8 wo1 = {0,0,0,0,0,0,0,0};
    if (j < 3) {
        wo0 = *(const bf16x8*)&w_out[j * W_STRIDE + 8 * g];
        wo1 = *(const bf16x8*)&w_out[j * W_STRIDE + 32 + 8 * g];
    }
    float bo = bout[j & 3];
    f32x4 zo = {bo, bo, bo, bo};
#pragma unroll
    for (int t = 0; t < 2; ++t) {
        bf16x8 a0 = *(const bf16x8*)&Hb[t][j * H_STRIDE + 8 * g];
        bf16x8 a1 = *(const bf16x8*)&Hb[t][j * H_STRIDE + 32 + 8 * g];
        f32x4 z = __builtin_amdgcn_mfma_f32_16x16x32_bf16(a0, wo0, zo, 0, 0, 0);
        f32x4 acc = __builtin_amdgcn_mfma_f32_16x16x32_bf16(a1, wo1, z, 0, 0, 0);
        if (j < 3) {
#pragma unroll
            for (int r = 0; r < 4; ++r) {
                float v = acc[r];
                v = 1.f / (1.f + __expf(-v));
                out[(size_t)(rb0 + t * 16 + 4 * g + r) * 3 + j] = v;
            }
        }
    }
}

extern "C" void kernel_launch(void* const* d_in, const int* in_sizes, int n_in,
                              void* d_out, int out_size, void* d_ws, size_t ws_size,
                              hipStream_t stream) {
    const float* x     = (const float*)d_in[0];
    const float* W_in  = (const float*)d_in[1];
    const float* b_in  = (const float*)d_in[2];
    const float* W_hid = (const float*)d_in[3];
    const float* b_hid = (const float*)d_in[4];
    const float* W_out = (const float*)d_in[5];
    const float* b_out = (const float*)d_in[6];
    float* out = (float*)d_out;

    int n = in_sizes[0] / 32;            // 1<<20
    int nblocks = n / 256;               // 8 waves * 2 tiles * 16 rows per block

    if (ws_size >= STAGE_BYTES) {
        hipLaunchKernelGGL(prep_kernel, dim3(40), dim3(512), 0, stream,
                           W_in, b_in, W_hid, b_hid, W_out, b_out,
                           (unsigned char*)d_ws);
        hipLaunchKernelGGL((mlp_kernel<true>), dim3(nblocks), dim3(512), 0, stream,
                           x, W_in, b_in, W_hid, b_hid, W_out, b_out,
                           (const uint4*)d_ws, out);
    } else {
        hipLaunchKernelGGL((mlp_kernel<false>), dim3(nblocks), dim3(512), 0, stream,
                           x, W_in, b_in, W_hid, b_hid, W_out, b_out,
                           (const uint4*)d_ws, out);
    }
}

// Round 3
// 57.023 us; speedup vs baseline: 1.7354x; 1.2066x over previous
//
#include <hip/hip_runtime.h>
#include <hip/hip_bf16.h>

// Fully fused MLP: 32 -> 64 -> (4x) 64 -> 3, relu hidden, sigmoid out.
// bf16 MFMA (16x16x32), fp32 accum. N = 1<<20 points, fp32 I/O.
//
// Round-3: operand-swapped MFMA (D[neuron][point] = W*H). D col = point = B-frag col
// of the next layer, so the point index is lane-invariant across layers. The neuron
// mismatch (source position 16nt+4g+r vs needed k-slot 32f+8g+4a+r) is a pure bit
// permutation pi(n): [n5 n4|n3 n2|n1 n0] -> [n5|n3 n2|n4|n1 n0], baked into the NEXT
// layer's weight columns at prep time. Layer handoff is then 100% lane-local:
//   h[f] = { cvtpk(relu(acc[2f].xy)), cvtpk(relu(acc[2f].zw)),
//            cvtpk(relu(acc[2f+1].xy)), cvtpk(relu(acc[2f+1].zw)) }
// -> NO LDS activation round-trip, no barriers between layers, no shuffles.
//
// Weights/biases live in a frag-major "register image" (59 frags x 64 lanes x 16B):
// every LDS read is  lane*16 + constant  -> conflict-free linear b128 reads.
// Each wave handles 256 points (8 iters x 2 16-point tiles); x prefetched 1 iter ahead.
//
// Frag map: 0..3 W_in[nt] | 4..35 W_hid[L][nt][f] | 36..37 W_out[f]
//           38..41 b_in[nt] | 42..57 b_hid[L][nt] | 58 b_out

typedef __attribute__((ext_vector_type(8))) short bf16x8;
typedef __attribute__((ext_vector_type(4))) float f32x4;

#define NFRAG 59
#define IMG_U4 (NFRAG * 64)          // 3776 uint4 = 60416 B

// packed f32x2 -> bf16x2, RNE, 1 instruction. lo = low 16 bits.
__device__ __forceinline__ unsigned cvtpk(float lo, float hi) {
    unsigned r;
    asm("v_cvt_pk_bf16_f32 %0, %1, %2" : "=v"(r) : "v"(lo), "v"(hi));
    return r;
}

// inverse of the neuron relabeling pi: k-slot s -> actual neuron index
__device__ __forceinline__ int pinv(int s) {
    return ((s >> 5) & 1) * 32 + ((s >> 2) & 1) * 16 + ((s >> 3) & 3) * 4 + (s & 3);
}

// value of image slot (frag F, lane) computed from the fp32 weights
__device__ uint4 frag_value(int F, int lane,
        const float* __restrict__ W_in,  const float* __restrict__ b_in,
        const float* __restrict__ W_hid, const float* __restrict__ b_hid,
        const float* __restrict__ W_out, const float* __restrict__ b_out) {
    const int j = lane & 15, g = lane >> 4;
    uint4 r = {0u, 0u, 0u, 0u};
    if (F < 4) {                                   // W_in A-frag, natural k
        const float* row = W_in + (F * 16 + j) * 32 + 8 * g;
        r.x = cvtpk(row[0], row[1]); r.y = cvtpk(row[2], row[3]);
        r.z = cvtpk(row[4], row[5]); r.w = cvtpk(row[6], row[7]);
    } else if (F < 36) {                           // W_hid A-frag, pi-relabeled k
        int q = F - 4, L = q >> 3, nt = (q >> 1) & 3, f = q & 1;
        const float* row = W_hid + (L * 64 + nt * 16 + j) * 64;
        int s0 = 32 * f + 8 * g;
        r.x = cvtpk(row[pinv(s0 + 0)], row[pinv(s0 + 1)]);
        r.y = cvtpk(row[pinv(s0 + 2)], row[pinv(s0 + 3)]);
        r.z = cvtpk(row[pinv(s0 + 4)], row[pinv(s0 + 5)]);
        r.w = cvtpk(row[pinv(s0 + 6)], row[pinv(s0 + 7)]);
    } else if (F < 38) {                           // W_out A-frag (rows 3..15 zero)
        int f = F - 36;
        if (j < 3) {
            const float* row = W_out + j * 64;
            int s0 = 32 * f + 8 * g;
            r.x = cvtpk(row[pinv(s0 + 0)], row[pinv(s0 + 1)]);
            r.y = cvtpk(row[pinv(s0 + 2)], row[pinv(s0 + 3)]);
            r.z = cvtpk(row[pinv(s0 + 4)], row[pinv(s0 + 5)]);
            r.w = cvtpk(row[pinv(s0 + 6)], row[pinv(s0 + 7)]);
        }
    } else {                                       // bias C-frags: f32x4, row = 4g+rr
        union { uint4 u; float f[4]; } t;
        if (F < 42) {
            int nt = F - 38;
#pragma unroll
            for (int rr = 0; rr < 4; ++rr) t.f[rr] = b_in[nt * 16 + 4 * g + rr];
        } else if (F < 58) {
            int q = F - 42, L = q >> 2, nt = q & 3;
#pragma unroll
            for (int rr = 0; rr < 4; ++rr) t.f[rr] = b_hid[L * 64 + nt * 16 + 4 * g + rr];
        } else {
#pragma unroll
            for (int rr = 0; rr < 4; ++rr) t.f[rr] = (4 * g + rr < 3) ? b_out[4 * g + rr] : 0.f;
        }
        r = t.u;
    }
    return r;
}

__global__ void prep_kernel(const float* __restrict__ W_in,  const float* __restrict__ b_in,
                            const float* __restrict__ W_hid, const float* __restrict__ b_hid,
                            const float* __restrict__ W_out, const float* __restrict__ b_out,
                            uint4* __restrict__ img) {
    img[blockIdx.x * 64 + threadIdx.x] =
        frag_value(blockIdx.x, threadIdx.x, W_in, b_in, W_hid, b_hid, W_out, b_out);
}

// relu + lane-local pi-pack: acc[4] (f32x4) -> h[2] (bf16x8)
__device__ __forceinline__ void relu_pack(const f32x4 a[4], bf16x8 h[2]) {
#pragma unroll
    for (int f = 0; f < 2; ++f) {
        union { bf16x8 v; unsigned u[4]; } t;
        t.u[0] = cvtpk(fmaxf(a[2 * f][0], 0.f), fmaxf(a[2 * f][1], 0.f));
        t.u[1] = cvtpk(fmaxf(a[2 * f][2], 0.f), fmaxf(a[2 * f][3], 0.f));
        t.u[2] = cvtpk(fmaxf(a[2 * f + 1][0], 0.f), fmaxf(a[2 * f + 1][1], 0.f));
        t.u[3] = cvtpk(fmaxf(a[2 * f + 1][2], 0.f), fmaxf(a[2 * f + 1][3], 0.f));
        h[f] = t.v;
    }
}

#define MFMA(a, b, c) __builtin_amdgcn_mfma_f32_16x16x32_bf16((a), (b), (c), 0, 0, 0)

template<bool FAST>
__global__ __launch_bounds__(512, 2) void mlp_kernel(
        const float* __restrict__ x, const uint4* __restrict__ img,
        const float* __restrict__ gW_in,  const float* __restrict__ gb_in,
        const float* __restrict__ gW_hid, const float* __restrict__ gb_hid,
        const float* __restrict__ gW_out, const float* __restrict__ gb_out,
        float* __restrict__ out) {
    __shared__ uint4 simg[IMG_U4];
    const int tid = threadIdx.x;

    if (FAST) {
#pragma unroll
        for (int i = 0; i < 8; ++i) {
            int idx = tid + i * 512;
            if (idx < IMG_U4) simg[idx] = img[idx];
        }
    } else {
        for (int idx = tid; idx < IMG_U4; idx += 512)
            simg[idx] = frag_value(idx >> 6, idx & 63,
                                   gW_in, gb_in, gW_hid, gb_hid, gW_out, gb_out);
    }
    __syncthreads();

    const int wave = tid >> 6, lane = tid & 63;
    const int j = lane & 15, g = lane >> 4;
    const uint4* lp = &simg[lane];               // frag F at lp[F*64] -> lane*16 + F*1024

    const int base = (blockIdx.x * 8 + wave) * 256;

    // prefetched raw x for the current iter (tiles A and B, 8 floats each)
    f32x4 xrA0, xrA1, xrB0, xrB1;
    {
        const float* p = x + (size_t)(base + j) * 32 + 8 * g;
        xrA0 = *(const f32x4*)p;         xrA1 = *(const f32x4*)(p + 4);
        xrB0 = *(const f32x4*)(p + 512); xrB1 = *(const f32x4*)(p + 516);
    }

#pragma unroll 1
    for (int it = 0; it < 8; ++it) {
        const int p0 = base + it * 32;

        // pack current x into B-frags
        union { bf16x8 v; unsigned u[4]; } xA, xB;
        xA.u[0] = cvtpk(xrA0[0], xrA0[1]); xA.u[1] = cvtpk(xrA0[2], xrA0[3]);
        xA.u[2] = cvtpk(xrA1[0], xrA1[1]); xA.u[3] = cvtpk(xrA1[2], xrA1[3]);
        xB.u[0] = cvtpk(xrB0[0], xrB0[1]); xB.u[1] = cvtpk(xrB0[2], xrB0[3]);
        xB.u[2] = cvtpk(xrB1[0], xrB1[1]); xB.u[3] = cvtpk(xrB1[2], xrB1[3]);

        // prefetch next iter's x (clamped reload of current on last iter)
        {
            const int pn = (it < 7) ? p0 + 32 : p0;
            const float* p = x + (size_t)(pn + j) * 32 + 8 * g;
            xrA0 = *(const f32x4*)p;         xrA1 = *(const f32x4*)(p + 4);
            xrB0 = *(const f32x4*)(p + 512); xrB1 = *(const f32x4*)(p + 516);
        }

        // ======== input layer ========
        f32x4 aA[4], aB[4];
#pragma unroll
        for (int nt = 0; nt < 4; ++nt) {
            bf16x8 w  = *(const bf16x8*)&lp[nt * 64];
            f32x4  bz = *(const f32x4*)&lp[(38 + nt) * 64];
            aA[nt] = MFMA(w, xA.v, bz);
            aB[nt] = MFMA(w, xB.v, bz);
        }
        bf16x8 hA[2], hB[2];
        relu_pack(aA, hA); relu_pack(aB, hB);

        // ======== 4 hidden layers ========
#pragma unroll 1
        for (int L = 0; L < 4; ++L) {
            const int wb = (4 + L * 8) * 64;
            const int bb = (42 + L * 4) * 64;
            bf16x8 w0[4], w1[4]; f32x4 bz[4];
#pragma unroll
            for (int nt = 0; nt < 4; ++nt) {
                w0[nt] = *(const bf16x8*)&lp[wb + (2 * nt) * 64];
                w1[nt] = *(const bf16x8*)&lp[wb + (2 * nt + 1) * 64];
                bz[nt] = *(const f32x4*)&lp[bb + nt * 64];
            }
#pragma unroll
            for (int nt = 0; nt < 4; ++nt) {
                aA[nt] = MFMA(w0[nt], hA[0], bz[nt]);
                aB[nt] = MFMA(w0[nt], hB[0], bz[nt]);
            }
#pragma unroll
            for (int nt = 0; nt < 4; ++nt) {
                aA[nt] = MFMA(w1[nt], hA[1], aA[nt]);
                aB[nt] = MFMA(w1[nt], hB[1], aB[nt]);
            }
            relu_pack(aA, hA); relu_pack(aB, hB);
        }

        // ======== output layer + sigmoid ========
        bf16x8 wo0 = *(const bf16x8*)&lp[36 * 64];
        bf16x8 wo1 = *(const bf16x8*)&lp[37 * 64];
        f32x4  bo  = *(const f32x4*)&lp[58 * 64];
        f32x4 zA = MFMA(wo0, hA[0], bo); zA = MFMA(wo1, hA[1], zA);
        f32x4 zB = MFMA(wo0, hB[0], bo); zB = MFMA(wo1, hB[1], zB);

        if (g == 0) {                       // rows 0..2 (= out neurons) live in g==0
            float* oA = out + (size_t)(p0 + j) * 3;
            float* oB = out + (size_t)(p0 + 16 + j) * 3;
#pragma unroll
            for (int r = 0; r < 3; ++r) {
                oA[r] = __builtin_amdgcn_rcpf(1.f + __expf(-zA[r]));
                oB[r] = __builtin_amdgcn_rcpf(1.f + __expf(-zB[r]));
            }
        }
    }
}

extern "C" void kernel_launch(void* const* d_in, const int* in_sizes, int n_in,
                              void* d_out, int out_size, void* d_ws, size_t ws_size,
                              hipStream_t stream) {
    const float* x     = (const float*)d_in[0];
    const float* W_in  = (const float*)d_in[1];
    const float* b_in  = (const float*)d_in[2];
    const float* W_hid = (const float*)d_in[3];
    const float* b_hid = (const float*)d_in[4];
    const float* W_out = (const float*)d_in[5];
    const float* b_out = (const float*)d_in[6];
    float* out = (float*)d_out;

    int n = in_sizes[0] / 32;              // 1<<20 points
    int nblocks = n / 2048;                // 8 waves * 256 points per block = 512 blocks

    if (ws_size >= (size_t)IMG_U4 * 16) {
        hipLaunchKernelGGL(prep_kernel, dim3(NFRAG), dim3(64), 0, stream,
                           W_in, b_in, W_hid, b_hid, W_out, b_out, (uint4*)d_ws);
        hipLaunchKernelGGL((mlp_kernel<true>), dim3(nblocks), dim3(512), 0, stream,
                           x, (const uint4*)d_ws,
                           W_in, b_in, W_hid, b_hid, W_out, b_out, out);
    } else {
        hipLaunchKernelGGL((mlp_kernel<false>), dim3(nblocks), dim3(512), 0, stream,
                           x, (const uint4*)d_ws,
                           W_in, b_in, W_hid, b_hid, W_out, b_out, out);
    }
}